// Round 6
// baseline (332.632 us; speedup 1.0000x reference)
//
#include <hip/hip_runtime.h>
#include <hip/hip_bf16.h>

#define S_LEN 1028
#define DH 64
#define NHEAD 16
#define NBATCH 8
#define L2N 3969
#define HIDN 32
#define KVB 64
#define NKT 17
#define NQT 17
#define NQT2 9          // 128-row q blocks
#define TILE_E 4096     // 64x64 elems per packed tile
#define LOG2E 1.4426950408889634f

typedef __bf16 bf16x8 __attribute__((ext_vector_type(8)));
typedef __bf16 bf16x4 __attribute__((ext_vector_type(4)));
typedef float f32x4 __attribute__((ext_vector_type(4)));

__device__ __forceinline__ bf16x8 cvt_bf16x8(float4 a, float4 b) {
  bf16x8 r;
  r[0] = (__bf16)a.x; r[1] = (__bf16)a.y; r[2] = (__bf16)a.z; r[3] = (__bf16)a.w;
  r[4] = (__bf16)b.x; r[5] = (__bf16)b.y; r[6] = (__bf16)b.z; r[7] = (__bf16)b.w;
  return r;
}

__device__ __forceinline__ f32x4 mfma16(bf16x8 a, bf16x8 b, f32x4 c) {
  return __builtin_amdgcn_mfma_f32_16x16x32_bf16(a, b, c, 0, 0, 0);
}

__device__ __forceinline__ float exp2_fast(float x) {
#if __has_builtin(__builtin_amdgcn_exp2f)
  return __builtin_amdgcn_exp2f(x);
#else
  return __expf(x * 0.6931471805599453f);
#endif
}

#define GLD16(gsrc, ldst)                                                     \
  __builtin_amdgcn_global_load_lds(                                           \
      (const __attribute__((address_space(1))) void*)(gsrc),                  \
      (__attribute__((address_space(3))) void*)(ldst), 16, 0, 0)

// ---------------- CPB MLP table, l-major: bt[l][h] ----------------
__global__ void cpb_table_lh(const float* __restrict__ rel,
                             const float* __restrict__ W1,
                             const float* __restrict__ b1,
                             const float* __restrict__ W2,
                             float* __restrict__ bt) {
  int i = blockIdx.x * blockDim.x + threadIdx.x;
  if (i >= L2N) return;
  float x = rel[2 * i], y = rel[2 * i + 1];
  float acc[NHEAD];
#pragma unroll
  for (int h = 0; h < NHEAD; ++h) acc[h] = 0.f;
#pragma unroll
  for (int j = 0; j < HIDN; ++j) {
    float t = fmaf(x, W1[j], fmaf(y, W1[HIDN + j], b1[j]));
    float g = 0.5f * t * (1.f + erff(t * 0.70710678118654752f));
#pragma unroll
    for (int h = 0; h < NHEAD; ++h) acc[h] = fmaf(g, W2[j * NHEAD + h], acc[h]);
  }
#pragma unroll
  for (int h = 0; h < NHEAD; ++h) bt[(size_t)i * NHEAD + h] = acc[h];
}

// ---------------- fused prep: bias expansion + KV pack in ONE dispatch ------
// blockIdx groups of 3: slot 0 -> bias row (first 1028 groups), slots 1,2 ->
// kv tiles. Interleaving keeps latency-bound (bias) and BW-bound (kv) blocks
// co-resident so they overlap instead of serializing.
__global__ __launch_bounds__(256) void prep_fused(
    const int* __restrict__ idx, const float* __restrict__ bt,
    const int* __restrict__ Rp, const float* __restrict__ kg,
    const float* __restrict__ vg, __bf16* __restrict__ bias,
    __bf16* __restrict__ Kb, __bf16* __restrict__ Vb) {
  const int tid = threadIdx.x;
  const int grp = blockIdx.x / 3, rem = blockIdx.x - 3 * grp;
  __shared__ __align__(16) char smem[64 * 68 * 4];

  if (rem == 0) {
    // ---------------- bias row qrow = grp ----------------
    const int qrow = grp;
    if (qrow >= S_LEN) return;
    __bf16(*strip)[264] = (__bf16(*)[264])smem;
    const int R = Rp[0];
    const bool qok = (qrow >= R);
    for (int k0 = 0; k0 < 1024; k0 += 256) {
      const int k = k0 + tid;
      const int l = idx[(size_t)qrow * S_LEN + k];
      const bool on = qok && (k >= R);
      const float4* btv = (const float4*)bt + (size_t)l * 4;
      float va[16];
      *(float4*)&va[0] = btv[0];
      *(float4*)&va[4] = btv[1];
      *(float4*)&va[8] = btv[2];
      *(float4*)&va[12] = btv[3];
#pragma unroll
      for (int h = 0; h < NHEAD; ++h)
        strip[h][tid] = on ? (__bf16)(va[h] * LOG2E) : (__bf16)0.f;
      __syncthreads();
      {
        const int h = tid >> 4, kg2 = tid & 15;
        bf16x8 w0 = *(bf16x8*)&strip[h][kg2 * 16];
        bf16x8 w1 = *(bf16x8*)&strip[h][kg2 * 16 + 8];
        __bf16* dst =
            bias + (size_t)h * S_LEN * S_LEN + (size_t)qrow * S_LEN + k0 + kg2 * 16;
        *(bf16x8*)dst = w0;
        *(bf16x8*)(dst + 8) = w1;
      }
      __syncthreads();
    }
    if (tid < 64) {
      const int kt = tid & 3, h = tid >> 2;
      const int k = 1024 + kt;
      const int l = idx[(size_t)qrow * S_LEN + k];
      const bool on = qok && (k >= R);
      const float v = bt[(size_t)l * NHEAD + h];
      bias[(size_t)h * S_LEN * S_LEN + (size_t)qrow * S_LEN + k] =
          on ? (__bf16)(v * LOG2E) : (__bf16)0.f;
    }
  } else {
    // ---------------- kv tile kvid = 2*grp + rem-1 ----------------
    const int kvid = 2 * grp + (rem - 1);
    if (kvid >= NKT * NBATCH * NHEAD) return;
    const int it = kvid % NKT, bh = kvid / NKT;
    const int kb = it * KVB;
    const float* kp = kg + (size_t)bh * S_LEN * DH;
    const float* vp = vg + (size_t)bh * S_LEN * DH;
    __bf16* kout = Kb + ((size_t)bh * NKT + it) * TILE_E;
    __bf16* vout = Vb + ((size_t)bh * NKT + it) * TILE_E;

    // K rows permuted+swizzled
    for (int i = tid; i < 512; i += 256) {
      const int rho = i >> 3, gx = i & 7;
      const int e = ((rho & 15) << 2) | (rho >> 4);
      const int key = kb + e;
      const int gsrc = gx ^ (rho & 7);
      float4 a = {0.f, 0.f, 0.f, 0.f}, b = {0.f, 0.f, 0.f, 0.f};
      if (key < S_LEN) {
        a = *(const float4*)(kp + (size_t)key * DH + gsrc * 8);
        b = *(const float4*)(kp + (size_t)key * DH + gsrc * 8 + 4);
      }
      *(bf16x8*)(kout + (size_t)rho * 64 + gx * 8) = cvt_bf16x8(a, b);
    }

    // V transpose through LDS
    float(*vt)[68] = (float(*)[68])smem;
    for (int i = tid; i < 1024; i += 256) {
      const int row = i >> 4, c4 = i & 15;
      const int key = kb + row;
      float4 a = {0.f, 0.f, 0.f, 0.f};
      if (key < S_LEN) a = *(const float4*)(vp + (size_t)key * DH + c4 * 4);
      *(float4*)&vt[row][c4 * 4] = a;
    }
    __syncthreads();
    for (int i = tid; i < 512; i += 256) {
      const int d = i >> 3, gx = i & 7;
      const int kg8 = (gx ^ (d & 7)) * 8;
      bf16x8 o;
#pragma unroll
      for (int j = 0; j < 8; ++j) o[j] = (__bf16)vt[kg8 + j][d];
      *(bf16x8*)(vout + (size_t)d * 64 + gx * 8) = o;
    }
  }
}

// ---------------- flash attention v5 ----------------------------------------
// 128 q-rows per block (2 sub-tiles u=0,1 sharing K/V staging + barriers);
// bias prefetched one K-tile ahead into registers (sets A/B);
// exp2 domain, bias as MFMA C-init, masked tail peeled, counted vmcnt.
#define LOADB(BB, ITC) do {                                                   \
    const int kkL = (ITC) * KVB + 4 * m;                                      \
    const bool okL = (kkL < S_LEN);                                           \
    _Pragma("unroll")                                                         \
    for (int u = 0; u < 2; ++u) {                                             \
      _Pragma("unroll")                                                       \
      for (int r = 0; r < 4; ++r) {                                           \
        bf16x4 z_; z_[0] = (__bf16)0.f; z_[1] = (__bf16)0.f;                  \
        z_[2] = (__bf16)0.f; z_[3] = (__bf16)0.f;                             \
        BB[u][r] = okL ? *(const bf16x4*)(bp + boff[u][r] + kkL) : z_;        \
      }                                                                       \
    }                                                                         \
  } while (0)

#define STEP(ITC, BB, MASKED, WAITN) do {                                     \
    const int buf_ = (ITC) & 1;                                               \
    __builtin_amdgcn_s_barrier();                                             \
    {                                                                         \
      const int nit_ = ((ITC) + 1 < NKT) ? (ITC) + 1 : 0;                     \
      const __bf16* gk_ = KbT + (size_t)nit_ * TILE_E + wave * 1024 + lo16;   \
      const __bf16* gv_ = VbT + (size_t)nit_ * TILE_E + wave * 1024 + lo16;   \
      __bf16* lk_ = &Kt[buf_ ^ 1][0][0] + wave * 1024;                        \
      __bf16* lv_ = &Vt[buf_ ^ 1][0][0] + wave * 1024;                        \
      GLD16(gk_, lk_); GLD16(gk_ + 512, lk_ + 512);                           \
      GLD16(gv_, lv_); GLD16(gv_ + 512, lv_ + 512);                           \
    }                                                                         \
    asm volatile("s_waitcnt vmcnt(" #WAITN ")" ::: "memory");                 \
    __builtin_amdgcn_s_barrier();                                             \
    __builtin_amdgcn_sched_barrier(0);                                        \
    const float kvf_ = (((ITC) * KVB + 4 * m) < S_LEN) ? 1.f : 0.f;           \
    _Pragma("unroll")                                                         \
    for (int u = 0; u < 2; ++u) {                                             \
      f32x4 sc_[4];                                                           \
      __builtin_amdgcn_s_setprio(1);                                          \
      _Pragma("unroll")                                                       \
      for (int c = 0; c < 4; ++c) {                                           \
        f32x4 a_;                                                             \
        _Pragma("unroll")                                                     \
        for (int r = 0; r < 4; ++r) a_[r] = (float)BB[u][r][c];               \
        _Pragma("unroll")                                                     \
        for (int dc = 0; dc < 2; ++dc) {                                      \
          bf16x8 kf_ = *(bf16x8*)&Kt[buf_][c * 16 + m][(dc * 32 + g * 8) ^ sw_m]; \
          a_ = mfma16(qf[u][dc], kf_, a_);                                    \
        }                                                                     \
        sc_[c] = a_;                                                          \
      }                                                                       \
      __builtin_amdgcn_s_setprio(0);                                          \
      _Pragma("unroll")                                                       \
      for (int r = 0; r < 4; ++r) {                                           \
        float p0_ = exp2_fast(sc_[0][r]);                                     \
        float p1_ = exp2_fast(sc_[1][r]);                                     \
        float p2_ = exp2_fast(sc_[2][r]);                                     \
        float p3_ = exp2_fast(sc_[3][r]);                                     \
        if (MASKED) lsum[u][r] += kvf_ * ((p0_ + p1_) + (p2_ + p3_));         \
        else        lsum[u][r] += (p0_ + p1_) + (p2_ + p3_);                  \
        bf16x4 pb_;                                                           \
        pb_[0] = (__bf16)p0_; pb_[1] = (__bf16)p1_;                           \
        pb_[2] = (__bf16)p2_; pb_[3] = (__bf16)p3_;                           \
        const int row_ = g * 4 + r;                                           \
        *(bf16x4*)&Pl[wave][row_][(4 * m) ^ ((row_ & 7) << 3)] = pb_;         \
      }                                                                       \
      __builtin_amdgcn_s_setprio(1);                                          \
      _Pragma("unroll")                                                       \
      for (int kc = 0; kc < 2; ++kc) {                                        \
        bf16x8 pf_ = *(bf16x8*)&Pl[wave][m][(kc * 32 + g * 8) ^ sw_m];        \
        _Pragma("unroll")                                                     \
        for (int t = 0; t < 4; ++t) {                                         \
          bf16x8 vf_ = *(bf16x8*)&Vt[buf_][t * 16 + m][(kc * 32 + g * 8) ^ sw_m]; \
          acc_o[u][t] = mfma16(pf_, vf_, acc_o[u][t]);                        \
        }                                                                     \
      }                                                                       \
      __builtin_amdgcn_s_setprio(0);                                          \
    }                                                                         \
  } while (0)

__global__ __launch_bounds__(256, 3) void flex_attn_v5(
    const float* __restrict__ qg, const __bf16* __restrict__ Kb,
    const __bf16* __restrict__ Vb, const __bf16* __restrict__ biasG,
    float* __restrict__ out) {
  const int b = blockIdx.z, h = blockIdx.y, qt = blockIdx.x;
  const int bh = b * NHEAD + h;
  const int tid = threadIdx.x;
  const int wave = tid >> 6, lane = tid & 63;
  const int g = lane >> 4, m = lane & 15;

  __shared__ __align__(16) __bf16 Kt[2][KVB][64];   // 16 KB
  __shared__ __align__(16) __bf16 Vt[2][DH][64];    // 16 KB
  __shared__ __align__(16) __bf16 Pl[4][16][64];    // 8 KB

  const __bf16* KbT = Kb + (size_t)bh * NKT * TILE_E;
  const __bf16* VbT = Vb + (size_t)bh * NKT * TILE_E;
  const __bf16* bp = biasG + (size_t)h * S_LEN * S_LEN;
  const float* qp = qg + (size_t)bh * S_LEN * DH;

  // Q fragments for both sub-tiles, pre-scaled by Dh^-0.5 * log2(e)
  const float qs = 0.125f * LOG2E;
  bf16x8 qf[2][2];
#pragma unroll
  for (int u = 0; u < 2; ++u) {
    const int qrow = qt * 128 + u * 64 + wave * 16 + m;
#pragma unroll
    for (int dc = 0; dc < 2; ++dc) {
      float4 a = {0.f, 0.f, 0.f, 0.f}, bb = {0.f, 0.f, 0.f, 0.f};
      if (qrow < S_LEN) {
        a = *(const float4*)(qp + (size_t)qrow * DH + dc * 32 + g * 8);
        bb = *(const float4*)(qp + (size_t)qrow * DH + dc * 32 + g * 8 + 4);
      }
      a.x *= qs; a.y *= qs; a.z *= qs; a.w *= qs;
      bb.x *= qs; bb.y *= qs; bb.z *= qs; bb.w *= qs;
      qf[u][dc] = cvt_bf16x8(a, bb);
    }
  }

  // bias row element-offsets (clamped q)
  int boff[2][4];
#pragma unroll
  for (int u = 0; u < 2; ++u)
#pragma unroll
    for (int r = 0; r < 4; ++r) {
      int qq = qt * 128 + u * 64 + wave * 16 + g * 4 + r;
      if (qq > S_LEN - 1) qq = S_LEN - 1;
      boff[u][r] = qq * S_LEN;
    }

  f32x4 acc_o[2][4];
#pragma unroll
  for (int u = 0; u < 2; ++u)
#pragma unroll
    for (int t = 0; t < 4; ++t) acc_o[u][t] = (f32x4){0.f, 0.f, 0.f, 0.f};
  float lsum[2][4];
#pragma unroll
  for (int u = 0; u < 2; ++u)
#pragma unroll
    for (int r = 0; r < 4; ++r) lsum[u][r] = 0.f;

  const int sw_m = (m & 7) << 3;
  const int lo16 = lane * 8;

  bf16x4 biasA[2][4], biasB[2][4];

  // prologue: bias(0) then stage tile 0 into buf 0 (order pinned for vmcnt math)
  LOADB(biasA, 0);
  __builtin_amdgcn_sched_barrier(0);
  {
    const __bf16* gk = KbT + wave * 1024 + lo16;
    const __bf16* gv = VbT + wave * 1024 + lo16;
    __bf16* lk = &Kt[0][0][0] + wave * 1024;
    __bf16* lv = &Vt[0][0][0] + wave * 1024;
    GLD16(gk, lk); GLD16(gk + 512, lk + 512);
    GLD16(gv, lv); GLD16(gv + 512, lv + 512);
  }

  // steady state: at STEP(it)'s wait, outstanding oldest->newest =
  // [tile-it GLD16 x4][bias(it+1) x8][tile(it+1) GLD16 x4] -> vmcnt(12)
  // drains exactly the current tile's staging (and all older bias).
  for (int it = 0; it < 16; it += 2) {
    LOADB(biasB, it + 1);
    __builtin_amdgcn_sched_barrier(0);
    STEP(it, biasA, false, 12);
    LOADB(biasA, it + 2);
    __builtin_amdgcn_sched_barrier(0);
    STEP(it + 1, biasB, false, 12);
  }
  // tail: outstanding = [bias16 x8][tile16 x4][dummy x4] -> vmcnt(4)
  STEP(16, biasA, true, 4);

  // epilogue
#pragma unroll
  for (int u = 0; u < 2; ++u) {
#pragma unroll
    for (int r = 0; r < 4; ++r) {
      float s = lsum[u][r];
      s += __shfl_xor(s, 1);
      s += __shfl_xor(s, 2);
      s += __shfl_xor(s, 4);
      s += __shfl_xor(s, 8);
      const int qq = qt * 128 + u * 64 + wave * 16 + g * 4 + r;
      if (qq >= S_LEN) continue;
      const float inv = 1.f / s;
      float* op = out + (((size_t)bh) * S_LEN + qq) * DH;
#pragma unroll
      for (int t = 0; t < 4; ++t) op[t * 16 + m] = acc_o[u][t][r] * inv;
    }
  }
}

// ================= fallback (ws too small for packed KV) =====================
__global__ __launch_bounds__(256) void bias_expand2(const int* __restrict__ idx,
                                                    const float* __restrict__ bt,
                                                    const int* __restrict__ Rp,
                                                    __bf16* __restrict__ bias) {
  const int qrow = blockIdx.x;
  const int R = Rp[0];
  const bool qok = (qrow >= R);
  const int tid = threadIdx.x;
  __shared__ __align__(16) __bf16 strip[NHEAD][264];
  for (int k0 = 0; k0 < 1024; k0 += 256) {
    const int k = k0 + tid;
    const int l = idx[(size_t)qrow * S_LEN + k];
    const bool on = qok && (k >= R);
    const float4* btv = (const float4*)bt + (size_t)l * 4;
    float va[16];
    *(float4*)&va[0] = btv[0];
    *(float4*)&va[4] = btv[1];
    *(float4*)&va[8] = btv[2];
    *(float4*)&va[12] = btv[3];
#pragma unroll
    for (int h = 0; h < NHEAD; ++h)
      strip[h][tid] = on ? (__bf16)(va[h] * LOG2E) : (__bf16)0.f;
    __syncthreads();
    {
      const int h = tid >> 4, kg2 = tid & 15;
      bf16x8 w0 = *(bf16x8*)&strip[h][kg2 * 16];
      bf16x8 w1 = *(bf16x8*)&strip[h][kg2 * 16 + 8];
      __bf16* dst = bias + (size_t)h * S_LEN * S_LEN + (size_t)qrow * S_LEN + k0 + kg2 * 16;
      *(bf16x8*)dst = w0;
      *(bf16x8*)(dst + 8) = w1;
    }
    __syncthreads();
  }
  if (tid < 64) {
    const int kt = tid & 3, h = tid >> 2;
    const int k = 1024 + kt;
    const int l = idx[(size_t)qrow * S_LEN + k];
    const bool on = qok && (k >= R);
    const float v = bt[(size_t)l * NHEAD + h];
    bias[(size_t)h * S_LEN * S_LEN + (size_t)qrow * S_LEN + k] =
        on ? (__bf16)(v * LOG2E) : (__bf16)0.f;
  }
}

__global__ __launch_bounds__(256, 4) void flex_attn_fast(
    const float* __restrict__ qg, const float* __restrict__ kg,
    const float* __restrict__ vg, const __bf16* __restrict__ biasG,
    float* __restrict__ out) {
  const int b = blockIdx.z, h = blockIdx.y, qt = blockIdx.x;
  const int tid = threadIdx.x;
  const int wave = tid >> 6, lane = tid & 63;
  const int g = lane >> 4, m = lane & 15;

  __shared__ __align__(16) __bf16 Kt[KVB][72];
  __shared__ __align__(16) __bf16 Vt[DH][72];
  __shared__ __align__(16) __bf16 Pl[4][16][72];

  const size_t base = ((size_t)(b * NHEAD + h)) * S_LEN * DH;
  const float* qp = qg + base;
  const float* kp = kg + base;
  const float* vp = vg + base;
  const __bf16* bp = biasG + (size_t)h * S_LEN * S_LEN;

  const int qrow = qt * 64 + wave * 16 + m;
  const float qs = 0.125f * LOG2E;
  bf16x8 qf[2];
#pragma unroll
  for (int dc = 0; dc < 2; ++dc) {
    float4 a = {0.f, 0.f, 0.f, 0.f}, bb = {0.f, 0.f, 0.f, 0.f};
    if (qrow < S_LEN) {
      a = *(const float4*)(qp + (size_t)qrow * DH + dc * 32 + g * 8);
      bb = *(const float4*)(qp + (size_t)qrow * DH + dc * 32 + g * 8 + 4);
    }
    a.x *= qs; a.y *= qs; a.z *= qs; a.w *= qs;
    bb.x *= qs; bb.y *= qs; bb.z *= qs; bb.w *= qs;
    qf[dc] = cvt_bf16x8(a, bb);
  }

  f32x4 acc_o[4];
#pragma unroll
  for (int t = 0; t < 4; ++t) acc_o[t] = (f32x4){0.f, 0.f, 0.f, 0.f};
  float mrow[4], lrow[4];
#pragma unroll
  for (int r = 0; r < 4; ++r) { mrow[r] = -1e30f; lrow[r] = 0.f; }

  const int qb4 = qt * 64 + wave * 16 + g * 4;
  const int eK = wave * 16 + (lane >> 2);
  const int rowK = ((eK & 3) << 4) | (eK >> 2);
  const int colK = (lane & 3) * 16;

  for (int it = 0; it < NKT; ++it) {
    const int kb = it * KVB;
    __syncthreads();
    {
      const int krow = kb + eK;
      float4 a0 = {0,0,0,0}, a1 = {0,0,0,0}, a2 = {0,0,0,0}, a3 = {0,0,0,0};
      if (krow < S_LEN) {
        const float* src = kp + (size_t)krow * DH + colK;
        a0 = *(const float4*)(src);
        a1 = *(const float4*)(src + 4);
        a2 = *(const float4*)(src + 8);
        a3 = *(const float4*)(src + 12);
      }
      *(bf16x8*)&Kt[rowK][colK] = cvt_bf16x8(a0, a1);
      *(bf16x8*)&Kt[rowK][colK + 8] = cvt_bf16x8(a2, a3);
    }
    {
      bf16x8 p0, p1;
#pragma unroll
      for (int t = 0; t < 8; ++t) {
        const int kr = kb + wave * 16 + t;
        p0[t] = (kr < S_LEN) ? (__bf16)vp[(size_t)kr * DH + lane] : (__bf16)0.f;
      }
#pragma unroll
      for (int t = 0; t < 8; ++t) {
        const int kr = kb + wave * 16 + 8 + t;
        p1[t] = (kr < S_LEN) ? (__bf16)vp[(size_t)kr * DH + lane] : (__bf16)0.f;
      }
      *(bf16x8*)&Vt[lane][wave * 16] = p0;
      *(bf16x8*)&Vt[lane][wave * 16 + 8] = p1;
    }

    const int kk = kb + 4 * m;
    const bool kvalid = (kk < S_LEN);
    bf16x4 bias4[4];
#pragma unroll
    for (int r = 0; r < 4; ++r) {
      const int qq = (qb4 + r < S_LEN) ? qb4 + r : S_LEN - 1;
      bf16x4 z; z[0] = (__bf16)0.f; z[1] = (__bf16)0.f; z[2] = (__bf16)0.f; z[3] = (__bf16)0.f;
      bias4[r] = kvalid ? *(const bf16x4*)(bp + (size_t)qq * S_LEN + kk) : z;
    }

    __syncthreads();

    f32x4 sc[4];
#pragma unroll
    for (int c = 0; c < 4; ++c) {
      f32x4 a = (f32x4){0.f, 0.f, 0.f, 0.f};
#pragma unroll
      for (int dc = 0; dc < 2; ++dc) {
        bf16x8 kf = *(bf16x8*)&Kt[c * 16 + m][dc * 32 + g * 8];
        a = mfma16(qf[dc], kf, a);
      }
      sc[c] = a;
    }

#pragma unroll
    for (int r = 0; r < 4; ++r) {
      float s[4];
#pragma unroll
      for (int c = 0; c < 4; ++c)
        s[c] = kvalid ? sc[c][r] + (float)bias4[r][c] : -1e30f;
      float mx = fmaxf(fmaxf(s[0], s[1]), fmaxf(s[2], s[3]));
      mx = fmaxf(mx, __shfl_xor(mx, 1));
      mx = fmaxf(mx, __shfl_xor(mx, 2));
      mx = fmaxf(mx, __shfl_xor(mx, 4));
      mx = fmaxf(mx, __shfl_xor(mx, 8));
      const float mnew = fmaxf(mrow[r], mx);
      const float alpha = exp2_fast(mrow[r] - mnew);
      float p0 = exp2_fast(s[0] - mnew), p1 = exp2_fast(s[1] - mnew);
      float p2 = exp2_fast(s[2] - mnew), p3 = exp2_fast(s[3] - mnew);
      float sum = (p0 + p1) + (p2 + p3);
      sum += __shfl_xor(sum, 1);
      sum += __shfl_xor(sum, 2);
      sum += __shfl_xor(sum, 4);
      sum += __shfl_xor(sum, 8);
      lrow[r] = lrow[r] * alpha + sum;
      mrow[r] = mnew;
      bf16x4 pb;
      pb[0] = (__bf16)p0; pb[1] = (__bf16)p1; pb[2] = (__bf16)p2; pb[3] = (__bf16)p3;
      *(bf16x4*)&Pl[wave][g * 4 + r][4 * m] = pb;
#pragma unroll
      for (int t = 0; t < 4; ++t) acc_o[t][r] *= alpha;
    }

#pragma unroll
    for (int kc = 0; kc < 2; ++kc) {
      bf16x8 pf = *(bf16x8*)&Pl[wave][m][kc * 32 + g * 8];
#pragma unroll
      for (int t = 0; t < 4; ++t) {
        bf16x8 vf = *(bf16x8*)&Vt[t * 16 + m][kc * 32 + g * 8];
        acc_o[t] = mfma16(pf, vf, acc_o[t]);
      }
    }
  }

#pragma unroll
  for (int r = 0; r < 4; ++r) {
    const int qq = qb4 + r;
    if (qq >= S_LEN) continue;
    const float inv = 1.f / lrow[r];
    float* op = out + (((size_t)(b * NHEAD + h)) * S_LEN + qq) * DH;
#pragma unroll
    for (int t = 0; t < 4; ++t) op[t * 16 + m] = acc_o[t][r] * inv;
  }
}

extern "C" void kernel_launch(void* const* d_in, const int* in_sizes, int n_in,
                              void* d_out, int out_size, void* d_ws, size_t ws_size,
                              hipStream_t stream) {
  const float* q = (const float*)d_in[0];
  const float* k = (const float*)d_in[1];
  const float* v = (const float*)d_in[2];
  const float* rel = (const float*)d_in[3];
  const float* W1 = (const float*)d_in[4];
  const float* b1 = (const float*)d_in[5];
  const float* W2 = (const float*)d_in[6];
  const int* idx = (const int*)d_in[7];
  const int* Rp = (const int*)d_in[8];
  float* out = (float*)d_out;

  const size_t bt_bytes = 1u << 18;                                   // 256 KB slot
  const size_t bias_bytes = (size_t)NHEAD * S_LEN * S_LEN * 2;        // 33.8 MB
  const size_t kv_bytes = (size_t)NBATCH * NHEAD * NKT * TILE_E * 2;  // 17.8 MB each

  if (ws_size >= bt_bytes + bias_bytes + 2 * kv_bytes) {
    float* bt = (float*)d_ws;
    __bf16* bias = (__bf16*)((char*)d_ws + bt_bytes);
    __bf16* Kb = (__bf16*)((char*)d_ws + bt_bytes + bias_bytes);
    __bf16* Vb = (__bf16*)((char*)d_ws + bt_bytes + bias_bytes + kv_bytes);
    cpb_table_lh<<<dim3((L2N + 255) / 256), dim3(256), 0, stream>>>(rel, W1, b1, W2, bt);
    prep_fused<<<dim3(3264), dim3(256), 0, stream>>>(idx, bt, Rp, k, v, bias, Kb, Vb);
    flex_attn_v5<<<dim3(NQT2, NHEAD, NBATCH), dim3(256), 0, stream>>>(q, Kb, Vb, bias, out);
  } else {
    float* bt = (float*)d_ws;
    __bf16* bias = (__bf16*)((char*)d_ws + bt_bytes);
    cpb_table_lh<<<dim3((L2N + 255) / 256), dim3(256), 0, stream>>>(rel, W1, b1, W2, bt);
    bias_expand2<<<dim3(S_LEN), dim3(256), 0, stream>>>(idx, bt, Rp, bias);
    flex_attn_fast<<<dim3(NQT, NHEAD, NBATCH), dim3(256), 0, stream>>>(q, k, v, bias, out);
  }
}

// Round 7
// 252.730 us; speedup vs baseline: 1.3162x; 1.3162x over previous
//
#include <hip/hip_runtime.h>
#include <hip/hip_bf16.h>

#define S_LEN 1028
#define DH 64
#define NHEAD 16
#define NBATCH 8
#define L2N 3969
#define HIDN 32
#define KVB 64
#define NKT 17
#define NQT 17
#define TILE_E 4096     // 64x64 elems per packed tile
#define LOG2E 1.4426950408889634f
#define NKV_TILES (NKT * NBATCH * NHEAD)   // 2176

typedef __bf16 bf16x8 __attribute__((ext_vector_type(8)));
typedef __bf16 bf16x4 __attribute__((ext_vector_type(4)));
typedef float f32x4 __attribute__((ext_vector_type(4)));

__device__ __forceinline__ bf16x8 cvt_bf16x8(float4 a, float4 b) {
  bf16x8 r;
  r[0] = (__bf16)a.x; r[1] = (__bf16)a.y; r[2] = (__bf16)a.z; r[3] = (__bf16)a.w;
  r[4] = (__bf16)b.x; r[5] = (__bf16)b.y; r[6] = (__bf16)b.z; r[7] = (__bf16)b.w;
  return r;
}

__device__ __forceinline__ f32x4 mfma16(bf16x8 a, bf16x8 b, f32x4 c) {
  return __builtin_amdgcn_mfma_f32_16x16x32_bf16(a, b, c, 0, 0, 0);
}

__device__ __forceinline__ float exp2_fast(float x) {
#if __has_builtin(__builtin_amdgcn_exp2f)
  return __builtin_amdgcn_exp2f(x);
#else
  return __expf(x * 0.6931471805599453f);
#endif
}

#define GLD16(gsrc, ldst)                                                     \
  __builtin_amdgcn_global_load_lds(                                           \
      (const __attribute__((address_space(1))) void*)(gsrc),                  \
      (__attribute__((address_space(3))) void*)(ldst), 16, 0, 0)

// ---------------- CPB MLP table: f32 bt[l][h] (fallback) + bf16 bt16[l][h]
// (main path, pre-scaled by log2e) ----------------
__global__ void cpb_table_lh(const float* __restrict__ rel,
                             const float* __restrict__ W1,
                             const float* __restrict__ b1,
                             const float* __restrict__ W2,
                             float* __restrict__ bt,
                             __bf16* __restrict__ bt16) {
  int i = blockIdx.x * blockDim.x + threadIdx.x;
  if (i >= L2N) return;
  float x = rel[2 * i], y = rel[2 * i + 1];
  float acc[NHEAD];
#pragma unroll
  for (int h = 0; h < NHEAD; ++h) acc[h] = 0.f;
#pragma unroll
  for (int j = 0; j < HIDN; ++j) {
    float t = fmaf(x, W1[j], fmaf(y, W1[HIDN + j], b1[j]));
    float g = 0.5f * t * (1.f + erff(t * 0.70710678118654752f));
#pragma unroll
    for (int h = 0; h < NHEAD; ++h) acc[h] = fmaf(g, W2[j * NHEAD + h], acc[h]);
  }
#pragma unroll
  for (int h = 0; h < NHEAD; ++h) {
    bt[(size_t)i * NHEAD + h] = acc[h];
    bt16[(size_t)i * NHEAD + h] = (__bf16)(acc[h] * LOG2E);
  }
}

// ---------------- fused prep v2: bias rows + KV tiles, one dispatch ---------
// blockIdx < 3084: groups of 3 -> {bias row, kv, kv}; >= 3084: leftover kv.
__global__ __launch_bounds__(256) void prep_fused2(
    const int* __restrict__ idx, const __bf16* __restrict__ bt16,
    const int* __restrict__ Rp, const float* __restrict__ kg,
    const float* __restrict__ vg, __bf16* __restrict__ bias,
    __bf16* __restrict__ Kb, __bf16* __restrict__ Vb) {
  const int tid = threadIdx.x;
  const int bid = blockIdx.x;
  __shared__ __align__(16) char smem[64 * 68 * 4];

  int kvid = -1, qrow = -1;
  if (bid < 3084) {
    const int grp = bid / 3, rem = bid - 3 * grp;
    if (rem == 0) qrow = grp;
    else kvid = 2 * grp + (rem - 1);
  } else {
    kvid = 2056 + (bid - 3084);
  }

  if (qrow >= 0) {
    // ---------------- bias row ----------------
    __bf16(*strip)[520] = (__bf16(*)[520])smem;  // [16 heads][512 k] (+pad)
    const int R = Rp[0];
    const bool qok = (qrow >= R);
    const __bf16* bsrc = bt16;
    bf16x8 z8;
#pragma unroll
    for (int j = 0; j < 8; ++j) z8[j] = (__bf16)0.f;

    for (int k0 = 0; k0 < 1024; k0 += 512) {
      const int ka = k0 + tid, kb2 = k0 + 256 + tid;
      const int la = idx[(size_t)qrow * S_LEN + ka];
      const int lb = idx[(size_t)qrow * S_LEN + kb2];
      bf16x8 va0 = *(const bf16x8*)(bsrc + (size_t)la * 16);
      bf16x8 va1 = *(const bf16x8*)(bsrc + (size_t)la * 16 + 8);
      bf16x8 vb0 = *(const bf16x8*)(bsrc + (size_t)lb * 16);
      bf16x8 vb1 = *(const bf16x8*)(bsrc + (size_t)lb * 16 + 8);
      const bool ona = qok && (ka >= R);
      const bool onb = qok && (kb2 >= R);
      if (!ona) { va0 = z8; va1 = z8; }
      if (!onb) { vb0 = z8; vb1 = z8; }
      // scatter into h-major strip (2B writes, lanes consecutive -> free)
#pragma unroll
      for (int h = 0; h < 8; ++h) {
        strip[h][tid] = va0[h];
        strip[h][256 + tid] = vb0[h];
        strip[8 + h][tid] = va1[h];
        strip[8 + h][256 + tid] = vb1[h];
      }
      __syncthreads();
      // coalesced write-out: thread t -> head t>>4, 32 k at (t&15)*32
      {
        const int h = tid >> 4, seg = tid & 15;
        __bf16* dst = bias + (size_t)h * S_LEN * S_LEN + (size_t)qrow * S_LEN +
                      k0 + seg * 32;
#pragma unroll
        for (int j = 0; j < 4; ++j) {
          bf16x8 w = *(bf16x8*)&strip[h][seg * 32 + j * 8];
          // 8B stores (row base only 8B-aligned for odd qrow)
          *(bf16x4*)(dst + j * 8) = *(bf16x4*)&w;
          *(bf16x4*)(dst + j * 8 + 4) = *((bf16x4*)&w + 1);
        }
      }
      __syncthreads();
    }
    // tail k = 1024..1027
    if (tid < 64) {
      const int kt = tid & 3, h = tid >> 2;
      const int k = 1024 + kt;
      const int l = idx[(size_t)qrow * S_LEN + k];
      const bool on = qok && (k >= R);
      bias[(size_t)h * S_LEN * S_LEN + (size_t)qrow * S_LEN + k] =
          on ? bt16[(size_t)l * 16 + h] : (__bf16)0.f;
    }
  } else {
    // ---------------- kv tile ----------------
    if (kvid >= NKV_TILES) return;
    const int it = kvid % NKT, bh = kvid / NKT;
    const int kb = it * KVB;
    const float* kp = kg + (size_t)bh * S_LEN * DH;
    const float* vp = vg + (size_t)bh * S_LEN * DH;
    __bf16* kout = Kb + ((size_t)bh * NKT + it) * TILE_E;
    __bf16* vout = Vb + ((size_t)bh * NKT + it) * TILE_E;

    // K rows permuted+swizzled
    for (int i = tid; i < 512; i += 256) {
      const int rho = i >> 3, gx = i & 7;
      const int e = ((rho & 15) << 2) | (rho >> 4);
      const int key = kb + e;
      const int gsrc = gx ^ (rho & 7);
      float4 a = {0.f, 0.f, 0.f, 0.f}, b = {0.f, 0.f, 0.f, 0.f};
      if (key < S_LEN) {
        a = *(const float4*)(kp + (size_t)key * DH + gsrc * 8);
        b = *(const float4*)(kp + (size_t)key * DH + gsrc * 8 + 4);
      }
      *(bf16x8*)(kout + (size_t)rho * 64 + gx * 8) = cvt_bf16x8(a, b);
    }

    // V transpose through LDS
    float(*vt)[68] = (float(*)[68])smem;
    for (int i = tid; i < 1024; i += 256) {
      const int row = i >> 4, c4 = i & 15;
      const int key = kb + row;
      float4 a = {0.f, 0.f, 0.f, 0.f};
      if (key < S_LEN) a = *(const float4*)(vp + (size_t)key * DH + c4 * 4);
      *(float4*)&vt[row][c4 * 4] = a;
    }
    __syncthreads();
    for (int i = tid; i < 512; i += 256) {
      const int d = i >> 3, gx = i & 7;
      const int kg8 = (gx ^ (d & 7)) * 8;
      bf16x8 o;
#pragma unroll
      for (int j = 0; j < 8; ++j) o[j] = (__bf16)vt[kg8 + j][d];
      *(bf16x8*)(vout + (size_t)d * 64 + gx * 8) = o;
    }
  }
}

// ---------------- flash attention v4 body (proven) + XCD-aware block map ----
#define TILE_STEP(ITC, MASKED) do {                                           \
    const int buf_ = (ITC) & 1;                                               \
    const int kk_ = (ITC) * KVB + 4 * m;                                      \
    bf16x4 bias4_[4];                                                         \
    _Pragma("unroll")                                                         \
    for (int r = 0; r < 4; ++r) {                                             \
      bf16x4 z_; z_[0] = (__bf16)0.f; z_[1] = (__bf16)0.f;                    \
      z_[2] = (__bf16)0.f; z_[3] = (__bf16)0.f;                               \
      bias4_[r] = (!(MASKED) || kk_ < S_LEN)                                  \
                      ? *(const bf16x4*)(brow[r] + kk_) : z_;                 \
    }                                                                         \
    __builtin_amdgcn_s_barrier();                                             \
    {                                                                         \
      const int nit_ = ((ITC) + 1 < NKT) ? (ITC) + 1 : 0;                     \
      const __bf16* gk_ = KbT + (size_t)nit_ * TILE_E + wave * 1024 + lo16;   \
      const __bf16* gv_ = VbT + (size_t)nit_ * TILE_E + wave * 1024 + lo16;   \
      __bf16* lk_ = &Kt[buf_ ^ 1][0][0] + wave * 1024;                        \
      __bf16* lv_ = &Vt[buf_ ^ 1][0][0] + wave * 1024;                        \
      GLD16(gk_, lk_); GLD16(gk_ + 512, lk_ + 512);                           \
      GLD16(gv_, lv_); GLD16(gv_ + 512, lv_ + 512);                           \
    }                                                                         \
    asm volatile("s_waitcnt vmcnt(8)" ::: "memory");                          \
    __builtin_amdgcn_s_barrier();                                             \
    __builtin_amdgcn_sched_barrier(0);                                        \
    f32x4 sc_[4];                                                             \
    _Pragma("unroll")                                                         \
    for (int c = 0; c < 4; ++c) {                                             \
      f32x4 a_;                                                               \
      _Pragma("unroll")                                                       \
      for (int r = 0; r < 4; ++r) a_[r] = (float)bias4_[r][c];                \
      _Pragma("unroll")                                                       \
      for (int dc = 0; dc < 2; ++dc) {                                        \
        bf16x8 kf_ = *(bf16x8*)&Kt[buf_][c * 16 + m][(dc * 32 + g * 8) ^ sw_m]; \
        a_ = mfma16(qf[dc], kf_, a_);                                         \
      }                                                                       \
      sc_[c] = a_;                                                            \
    }                                                                         \
    _Pragma("unroll")                                                         \
    for (int r = 0; r < 4; ++r) {                                             \
      float p0_ = exp2_fast(sc_[0][r]);                                       \
      float p1_ = exp2_fast(sc_[1][r]);                                       \
      float p2_ = exp2_fast(sc_[2][r]);                                       \
      float p3_ = exp2_fast(sc_[3][r]);                                       \
      if (MASKED) {                                                           \
        const float kvf_ = (kk_ < S_LEN) ? 1.f : 0.f;                         \
        lsum[r] += kvf_ * ((p0_ + p1_) + (p2_ + p3_));                        \
      } else {                                                                \
        lsum[r] += (p0_ + p1_) + (p2_ + p3_);                                 \
      }                                                                       \
      bf16x4 pb_;                                                             \
      pb_[0] = (__bf16)p0_; pb_[1] = (__bf16)p1_;                             \
      pb_[2] = (__bf16)p2_; pb_[3] = (__bf16)p3_;                             \
      const int row_ = g * 4 + r;                                             \
      *(bf16x4*)&Pl[wave][row_][(4 * m) ^ ((row_ & 7) << 3)] = pb_;           \
    }                                                                         \
    _Pragma("unroll")                                                         \
    for (int kc = 0; kc < 2; ++kc) {                                          \
      bf16x8 pf_ = *(bf16x8*)&Pl[wave][m][(kc * 32 + g * 8) ^ sw_m];          \
      _Pragma("unroll")                                                       \
      for (int t = 0; t < 4; ++t) {                                           \
        bf16x8 vf_ = *(bf16x8*)&Vt[buf_][t * 16 + m][(kc * 32 + g * 8) ^ sw_m]; \
        acc_o[t] = mfma16(pf_, vf_, acc_o[t]);                                \
      }                                                                       \
    }                                                                         \
  } while (0)

__global__ __launch_bounds__(256, 4) void flex_attn_v4x(
    const float* __restrict__ qg, const __bf16* __restrict__ Kb,
    const __bf16* __restrict__ Vb, const __bf16* __restrict__ biasG,
    float* __restrict__ out) {
  // XCD-aware map: linear id = h + 16*y -> id%8 = h%8, so each XCD
  // serves 2 heads and their 2.1 MB bias planes stay L2-resident.
  const int h = blockIdx.x;
  const int y = blockIdx.y;
  const int qt = y % NQT;
  const int b = y / NQT;
  const int bh = b * NHEAD + h;
  const int tid = threadIdx.x;
  const int wave = tid >> 6, lane = tid & 63;
  const int g = lane >> 4, m = lane & 15;

  __shared__ __align__(16) __bf16 Kt[2][KVB][64];   // 16 KB
  __shared__ __align__(16) __bf16 Vt[2][DH][64];    // 16 KB
  __shared__ __align__(16) __bf16 Pl[4][16][64];    // 8 KB

  const __bf16* KbT = Kb + (size_t)bh * NKT * TILE_E;
  const __bf16* VbT = Vb + (size_t)bh * NKT * TILE_E;
  const __bf16* bp = biasG + (size_t)h * S_LEN * S_LEN;
  const float* qp = qg + (size_t)bh * S_LEN * DH;

  // Q fragments, pre-scaled by Dh^-0.5 * log2(e)
  const int qrow = qt * 64 + wave * 16 + m;
  const float qs = 0.125f * LOG2E;
  bf16x8 qf[2];
#pragma unroll
  for (int dc = 0; dc < 2; ++dc) {
    float4 a = {0.f, 0.f, 0.f, 0.f}, bb = {0.f, 0.f, 0.f, 0.f};
    if (qrow < S_LEN) {
      a = *(const float4*)(qp + (size_t)qrow * DH + dc * 32 + g * 8);
      bb = *(const float4*)(qp + (size_t)qrow * DH + dc * 32 + g * 8 + 4);
    }
    a.x *= qs; a.y *= qs; a.z *= qs; a.w *= qs;
    bb.x *= qs; bb.y *= qs; bb.z *= qs; bb.w *= qs;
    qf[dc] = cvt_bf16x8(a, bb);
  }

  const int qb4 = qt * 64 + wave * 16 + g * 4;
  const __bf16* brow[4];
#pragma unroll
  for (int r = 0; r < 4; ++r) {
    int qq = qb4 + r; if (qq > S_LEN - 1) qq = S_LEN - 1;
    brow[r] = bp + (size_t)qq * S_LEN;
  }

  f32x4 acc_o[4];
#pragma unroll
  for (int t = 0; t < 4; ++t) acc_o[t] = (f32x4){0.f, 0.f, 0.f, 0.f};
  float lsum[4] = {0.f, 0.f, 0.f, 0.f};

  const int sw_m = (m & 7) << 3;
  const int lo16 = lane * 8;

  // prologue: stage tile 0 into buf 0
  {
    const __bf16* gk = KbT + wave * 1024 + lo16;
    const __bf16* gv = VbT + wave * 1024 + lo16;
    __bf16* lk = &Kt[0][0][0] + wave * 1024;
    __bf16* lv = &Vt[0][0][0] + wave * 1024;
    GLD16(gk, lk); GLD16(gk + 512, lk + 512);
    GLD16(gv, lv); GLD16(gv + 512, lv + 512);
  }

#pragma unroll 2
  for (int it = 0; it < 16; ++it) {
    TILE_STEP(it, false);
  }
  TILE_STEP(16, true);

  // epilogue: reduce lsum across the 16 m-lanes, write O
#pragma unroll
  for (int r = 0; r < 4; ++r) {
    float s = lsum[r];
    s += __shfl_xor(s, 1);
    s += __shfl_xor(s, 2);
    s += __shfl_xor(s, 4);
    s += __shfl_xor(s, 8);
    const int qq = qb4 + r;
    if (qq >= S_LEN) continue;
    const float inv = 1.f / s;
    float* op = out + (((size_t)bh) * S_LEN + qq) * DH;
#pragma unroll
    for (int t = 0; t < 4; ++t) op[t * 16 + m] = acc_o[t][r] * inv;
  }
}

// ================= fallback (ws too small for packed KV) =====================
__global__ __launch_bounds__(256) void bias_expand2(const int* __restrict__ idx,
                                                    const float* __restrict__ bt,
                                                    const int* __restrict__ Rp,
                                                    __bf16* __restrict__ bias) {
  const int qrow = blockIdx.x;
  const int R = Rp[0];
  const bool qok = (qrow >= R);
  const int tid = threadIdx.x;
  __shared__ __align__(16) __bf16 strip[NHEAD][264];
  for (int k0 = 0; k0 < 1024; k0 += 256) {
    const int k = k0 + tid;
    const int l = idx[(size_t)qrow * S_LEN + k];
    const bool on = qok && (k >= R);
    const float4* btv = (const float4*)bt + (size_t)l * 4;
    float va[16];
    *(float4*)&va[0] = btv[0];
    *(float4*)&va[4] = btv[1];
    *(float4*)&va[8] = btv[2];
    *(float4*)&va[12] = btv[3];
#pragma unroll
    for (int h = 0; h < NHEAD; ++h)
      strip[h][tid] = on ? (__bf16)(va[h] * LOG2E) : (__bf16)0.f;
    __syncthreads();
    {
      const int h = tid >> 4, kg2 = tid & 15;
      bf16x8 w0 = *(bf16x8*)&strip[h][kg2 * 16];
      bf16x8 w1 = *(bf16x8*)&strip[h][kg2 * 16 + 8];
      __bf16* dst = bias + (size_t)h * S_LEN * S_LEN + (size_t)qrow * S_LEN + k0 + kg2 * 16;
      *(bf16x8*)dst = w0;
      *(bf16x8*)(dst + 8) = w1;
    }
    __syncthreads();
  }
  if (tid < 64) {
    const int kt = tid & 3, h = tid >> 2;
    const int k = 1024 + kt;
    const int l = idx[(size_t)qrow * S_LEN + k];
    const bool on = qok && (k >= R);
    const float v = bt[(size_t)l * NHEAD + h];
    bias[(size_t)h * S_LEN * S_LEN + (size_t)qrow * S_LEN + k] =
        on ? (__bf16)(v * LOG2E) : (__bf16)0.f;
  }
}

__global__ __launch_bounds__(256, 4) void flex_attn_fast(
    const float* __restrict__ qg, const float* __restrict__ kg,
    const float* __restrict__ vg, const __bf16* __restrict__ biasG,
    float* __restrict__ out) {
  const int b = blockIdx.z, h = blockIdx.y, qt = blockIdx.x;
  const int tid = threadIdx.x;
  const int wave = tid >> 6, lane = tid & 63;
  const int g = lane >> 4, m = lane & 15;

  __shared__ __align__(16) __bf16 Kt[KVB][72];
  __shared__ __align__(16) __bf16 Vt[DH][72];
  __shared__ __align__(16) __bf16 Pl[4][16][72];

  const size_t base = ((size_t)(b * NHEAD + h)) * S_LEN * DH;
  const float* qp = qg + base;
  const float* kp = kg + base;
  const float* vp = vg + base;
  const __bf16* bp = biasG + (size_t)h * S_LEN * S_LEN;

  const int qrow = qt * 64 + wave * 16 + m;
  const float qs = 0.125f * LOG2E;
  bf16x8 qf[2];
#pragma unroll
  for (int dc = 0; dc < 2; ++dc) {
    float4 a = {0.f, 0.f, 0.f, 0.f}, bb = {0.f, 0.f, 0.f, 0.f};
    if (qrow < S_LEN) {
      a = *(const float4*)(qp + (size_t)qrow * DH + dc * 32 + g * 8);
      bb = *(const float4*)(qp + (size_t)qrow * DH + dc * 32 + g * 8 + 4);
    }
    a.x *= qs; a.y *= qs; a.z *= qs; a.w *= qs;
    bb.x *= qs; bb.y *= qs; bb.z *= qs; bb.w *= qs;
    qf[dc] = cvt_bf16x8(a, bb);
  }

  f32x4 acc_o[4];
#pragma unroll
  for (int t = 0; t < 4; ++t) acc_o[t] = (f32x4){0.f, 0.f, 0.f, 0.f};
  float mrow[4], lrow[4];
#pragma unroll
  for (int r = 0; r < 4; ++r) { mrow[r] = -1e30f; lrow[r] = 0.f; }

  const int qb4 = qt * 64 + wave * 16 + g * 4;
  const int eK = wave * 16 + (lane >> 2);
  const int rowK = ((eK & 3) << 4) | (eK >> 2);
  const int colK = (lane & 3) * 16;

  for (int it = 0; it < NKT; ++it) {
    const int kb = it * KVB;
    __syncthreads();
    {
      const int krow = kb + eK;
      float4 a0 = {0,0,0,0}, a1 = {0,0,0,0}, a2 = {0,0,0,0}, a3 = {0,0,0,0};
      if (krow < S_LEN) {
        const float* src = kp + (size_t)krow * DH + colK;
        a0 = *(const float4*)(src);
        a1 = *(const float4*)(src + 4);
        a2 = *(const float4*)(src + 8);
        a3 = *(const float4*)(src + 12);
      }
      *(bf16x8*)&Kt[rowK][colK] = cvt_bf16x8(a0, a1);
      *(bf16x8*)&Kt[rowK][colK + 8] = cvt_bf16x8(a2, a3);
    }
    {
      bf16x8 p0, p1;
#pragma unroll
      for (int t = 0; t < 8; ++t) {
        const int kr = kb + wave * 16 + t;
        p0[t] = (kr < S_LEN) ? (__bf16)vp[(size_t)kr * DH + lane] : (__bf16)0.f;
      }
#pragma unroll
      for (int t = 0; t < 8; ++t) {
        const int kr = kb + wave * 16 + 8 + t;
        p1[t] = (kr < S_LEN) ? (__bf16)vp[(size_t)kr * DH + lane] : (__bf16)0.f;
      }
      *(bf16x8*)&Vt[lane][wave * 16] = p0;
      *(bf16x8*)&Vt[lane][wave * 16 + 8] = p1;
    }

    const int kk = kb + 4 * m;
    const bool kvalid = (kk < S_LEN);
    bf16x4 bias4[4];
#pragma unroll
    for (int r = 0; r < 4; ++r) {
      const int qq = (qb4 + r < S_LEN) ? qb4 + r : S_LEN - 1;
      bf16x4 z; z[0] = (__bf16)0.f; z[1] = (__bf16)0.f; z[2] = (__bf16)0.f; z[3] = (__bf16)0.f;
      bias4[r] = kvalid ? *(const bf16x4*)(bp + (size_t)qq * S_LEN + kk) : z;
    }

    __syncthreads();

    f32x4 sc[4];
#pragma unroll
    for (int c = 0; c < 4; ++c) {
      f32x4 a = (f32x4){0.f, 0.f, 0.f, 0.f};
#pragma unroll
      for (int dc = 0; dc < 2; ++dc) {
        bf16x8 kf = *(bf16x8*)&Kt[c * 16 + m][dc * 32 + g * 8];
        a = mfma16(qf[dc], kf, a);
      }
      sc[c] = a;
    }

#pragma unroll
    for (int r = 0; r < 4; ++r) {
      float s[4];
#pragma unroll
      for (int c = 0; c < 4; ++c)
        s[c] = kvalid ? sc[c][r] + (float)bias4[r][c] : -1e30f;
      float mx = fmaxf(fmaxf(s[0], s[1]), fmaxf(s[2], s[3]));
      mx = fmaxf(mx, __shfl_xor(mx, 1));
      mx = fmaxf(mx, __shfl_xor(mx, 2));
      mx = fmaxf(mx, __shfl_xor(mx, 4));
      mx = fmaxf(mx, __shfl_xor(mx, 8));
      const float mnew = fmaxf(mrow[r], mx);
      const float alpha = exp2_fast(mrow[r] - mnew);
      float p0 = exp2_fast(s[0] - mnew), p1 = exp2_fast(s[1] - mnew);
      float p2 = exp2_fast(s[2] - mnew), p3 = exp2_fast(s[3] - mnew);
      float sum = (p0 + p1) + (p2 + p3);
      sum += __shfl_xor(sum, 1);
      sum += __shfl_xor(sum, 2);
      sum += __shfl_xor(sum, 4);
      sum += __shfl_xor(sum, 8);
      lrow[r] = lrow[r] * alpha + sum;
      mrow[r] = mnew;
      bf16x4 pb;
      pb[0] = (__bf16)p0; pb[1] = (__bf16)p1; pb[2] = (__bf16)p2; pb[3] = (__bf16)p3;
      *(bf16x4*)&Pl[wave][g * 4 + r][4 * m] = pb;
#pragma unroll
      for (int t = 0; t < 4; ++t) acc_o[t][r] *= alpha;
    }

#pragma unroll
    for (int kc = 0; kc < 2; ++kc) {
      bf16x8 pf = *(bf16x8*)&Pl[wave][m][kc * 32 + g * 8];
#pragma unroll
      for (int t = 0; t < 4; ++t) {
        bf16x8 vf = *(bf16x8*)&Vt[t * 16 + m][kc * 32 + g * 8];
        acc_o[t] = mfma16(pf, vf, acc_o[t]);
      }
    }
  }

#pragma unroll
  for (int r = 0; r < 4; ++r) {
    const int qq = qb4 + r;
    if (qq >= S_LEN) continue;
    const float inv = 1.f / lrow[r];
    float* op = out + (((size_t)(b * NHEAD + h)) * S_LEN + qq) * DH;
#pragma unroll
    for (int t = 0; t < 4; ++t) op[t * 16 + m] = acc_o[t][r] * inv;
  }
}

extern "C" void kernel_launch(void* const* d_in, const int* in_sizes, int n_in,
                              void* d_out, int out_size, void* d_ws, size_t ws_size,
                              hipStream_t stream) {
  const float* q = (const float*)d_in[0];
  const float* k = (const float*)d_in[1];
  const float* v = (const float*)d_in[2];
  const float* rel = (const float*)d_in[3];
  const float* W1 = (const float*)d_in[4];
  const float* b1 = (const float*)d_in[5];
  const float* W2 = (const float*)d_in[6];
  const int* idx = (const int*)d_in[7];
  const int* Rp = (const int*)d_in[8];
  float* out = (float*)d_out;

  const size_t bt_bytes = 1u << 18;                                   // 256 KB slot (f32)
  const size_t bt16_bytes = 1u << 17;                                 // 128 KB slot (bf16)
  const size_t bias_bytes = (size_t)NHEAD * S_LEN * S_LEN * 2;        // 33.8 MB
  const size_t kv_bytes = (size_t)NBATCH * NHEAD * NKT * TILE_E * 2;  // 17.8 MB each

  float* bt = (float*)d_ws;
  __bf16* bt16 = (__bf16*)((char*)d_ws + bt_bytes);
  __bf16* bias = (__bf16*)((char*)d_ws + bt_bytes + bt16_bytes);
  __bf16* Kb = (__bf16*)((char*)d_ws + bt_bytes + bt16_bytes + bias_bytes);
  __bf16* Vb = (__bf16*)((char*)d_ws + bt_bytes + bt16_bytes + bias_bytes + kv_bytes);

  if (ws_size >= bt_bytes + bt16_bytes + bias_bytes + 2 * kv_bytes) {
    cpb_table_lh<<<dim3((L2N + 255) / 256), dim3(256), 0, stream>>>(rel, W1, b1, W2, bt, bt16);
    prep_fused2<<<dim3(3204), dim3(256), 0, stream>>>(idx, bt16, Rp, k, v, bias, Kb, Vb);
    flex_attn_v4x<<<dim3(NHEAD, NQT * NBATCH, 1), dim3(256), 0, stream>>>(q, Kb, Vb, bias, out);
  } else {
    // fallback: f32 bt + unpacked KV (kernels proven in round 2/5)
    __bf16* bias_f = (__bf16*)((char*)d_ws + bt_bytes + bt16_bytes);
    cpb_table_lh<<<dim3((L2N + 255) / 256), dim3(256), 0, stream>>>(rel, W1, b1, W2, bt, bt16);
    bias_expand2<<<dim3(S_LEN), dim3(256), 0, stream>>>(idx, bt, Rp, bias_f);
    flex_attn_fast<<<dim3(NQT, NHEAD, NBATCH), dim3(256), 0, stream>>>(q, k, v, bias_f, out);
  }
}

// Round 8
// 247.142 us; speedup vs baseline: 1.3459x; 1.0226x over previous
//
#include <hip/hip_runtime.h>
#include <hip/hip_bf16.h>

#define S_LEN 1028
#define DH 64
#define NHEAD 16
#define NBATCH 8
#define L2N 3969
#define HIDN 32
#define KVB 64
#define NKT 17
#define NQT 17
#define TILE_E 4096     // 64x64 elems per packed tile
#define LOG2E 1.4426950408889634f
#define NKV_TILES (NKT * NBATCH * NHEAD)   // 2176
#define SPITCH 1040     // padded bias row pitch (16B-aligned rows)
#define SPLANE ((size_t)S_LEN * SPITCH)

typedef __bf16 bf16x8 __attribute__((ext_vector_type(8)));
typedef __bf16 bf16x4 __attribute__((ext_vector_type(4)));
typedef float f32x4 __attribute__((ext_vector_type(4)));

__device__ __forceinline__ bf16x8 cvt_bf16x8(float4 a, float4 b) {
  bf16x8 r;
  r[0] = (__bf16)a.x; r[1] = (__bf16)a.y; r[2] = (__bf16)a.z; r[3] = (__bf16)a.w;
  r[4] = (__bf16)b.x; r[5] = (__bf16)b.y; r[6] = (__bf16)b.z; r[7] = (__bf16)b.w;
  return r;
}

__device__ __forceinline__ f32x4 mfma16(bf16x8 a, bf16x8 b, f32x4 c) {
  return __builtin_amdgcn_mfma_f32_16x16x32_bf16(a, b, c, 0, 0, 0);
}

__device__ __forceinline__ float exp2_fast(float x) {
#if __has_builtin(__builtin_amdgcn_exp2f)
  return __builtin_amdgcn_exp2f(x);
#else
  return __expf(x * 0.6931471805599453f);
#endif
}

#define GLD16(gsrc, ldst)                                                     \
  __builtin_amdgcn_global_load_lds(                                           \
      (const __attribute__((address_space(1))) void*)(gsrc),                  \
      (__attribute__((address_space(3))) void*)(ldst), 16, 0, 0)

// ---------------- CPB MLP table: f32 bt[l][h] (fallback) + bf16 bt16[l][h] --
__global__ void cpb_table_lh(const float* __restrict__ rel,
                             const float* __restrict__ W1,
                             const float* __restrict__ b1,
                             const float* __restrict__ W2,
                             float* __restrict__ bt,
                             __bf16* __restrict__ bt16) {
  int i = blockIdx.x * blockDim.x + threadIdx.x;
  if (i >= L2N) return;
  float x = rel[2 * i], y = rel[2 * i + 1];
  float acc[NHEAD];
#pragma unroll
  for (int h = 0; h < NHEAD; ++h) acc[h] = 0.f;
#pragma unroll
  for (int j = 0; j < HIDN; ++j) {
    float t = fmaf(x, W1[j], fmaf(y, W1[HIDN + j], b1[j]));
    float g = 0.5f * t * (1.f + erff(t * 0.70710678118654752f));
#pragma unroll
    for (int h = 0; h < NHEAD; ++h) acc[h] = fmaf(g, W2[j * NHEAD + h], acc[h]);
  }
#pragma unroll
  for (int h = 0; h < NHEAD; ++h) {
    bt[(size_t)i * NHEAD + h] = acc[h];
    bt16[(size_t)i * NHEAD + h] = (__bf16)(acc[h] * LOG2E);
  }
}

// ---------------- fused prep v3: bias HALF-rows + KV tiles, one dispatch ----
// bid < 4112: even -> bias half-row (2056), odd -> kv tile (2056);
// bid >= 4112: leftover kv tiles (120). Half-rows double bias parallelism.
__global__ __launch_bounds__(256) void prep_fused3(
    const int* __restrict__ idx, const __bf16* __restrict__ bt16,
    const int* __restrict__ Rp, const float* __restrict__ kg,
    const float* __restrict__ vg, __bf16* __restrict__ bias,
    __bf16* __restrict__ Kb, __bf16* __restrict__ Vb) {
  const int tid = threadIdx.x;
  const int bid = blockIdx.x;
  __shared__ __align__(16) char smem[64 * 68 * 4];

  int kvid = -1, bias_id = -1;
  if (bid < 4112) {
    if ((bid & 1) == 0) bias_id = bid >> 1;
    else kvid = bid >> 1;
  } else {
    kvid = 2056 + (bid - 4112);
  }

  if (bias_id >= 0) {
    // ---------------- bias half-row ----------------
    const int qrow = bias_id >> 1, half = bias_id & 1;
    const int base = half * 512;
    __bf16(*strip)[520] = (__bf16(*)[520])smem;  // [16 heads][512 k] (+pad)
    const int R = Rp[0];
    const bool qok = (qrow >= R);
    bf16x8 z8;
#pragma unroll
    for (int j = 0; j < 8; ++j) z8[j] = (__bf16)0.f;

    const int ka = base + tid, kb2 = base + 256 + tid;
    const int la = idx[(size_t)qrow * S_LEN + ka];
    const int lb = idx[(size_t)qrow * S_LEN + kb2];
    bf16x8 va0 = *(const bf16x8*)(bt16 + (size_t)la * 16);
    bf16x8 va1 = *(const bf16x8*)(bt16 + (size_t)la * 16 + 8);
    bf16x8 vb0 = *(const bf16x8*)(bt16 + (size_t)lb * 16);
    bf16x8 vb1 = *(const bf16x8*)(bt16 + (size_t)lb * 16 + 8);
    const bool ona = qok && (ka >= R);
    const bool onb = qok && (kb2 >= R);
    if (!ona) { va0 = z8; va1 = z8; }
    if (!onb) { vb0 = z8; vb1 = z8; }
#pragma unroll
    for (int h = 0; h < 8; ++h) {
      strip[h][tid] = va0[h];
      strip[h][256 + tid] = vb0[h];
      strip[8 + h][tid] = va1[h];
      strip[8 + h][256 + tid] = vb1[h];
    }
    __syncthreads();
    // coalesced write-out: thread t -> head t>>4, 32 k at (t&15)*32 (16B rows)
    {
      const int h = tid >> 4, seg = tid & 15;
      __bf16* dst = bias + (size_t)h * SPLANE + (size_t)qrow * SPITCH + base + seg * 32;
#pragma unroll
      for (int j = 0; j < 4; ++j)
        *(bf16x8*)(dst + j * 8) = *(bf16x8*)&strip[h][seg * 32 + j * 8];
    }
    // tail k = 1024..1027 (only the upper half-block)
    if (half && tid < 64) {
      const int kt = tid & 3, h = tid >> 2;
      const int k = 1024 + kt;
      const int l = idx[(size_t)qrow * S_LEN + k];
      const bool on = qok && (k >= R);
      bias[(size_t)h * SPLANE + (size_t)qrow * SPITCH + k] =
          on ? bt16[(size_t)l * 16 + h] : (__bf16)0.f;
    }
  } else {
    // ---------------- kv tile ----------------
    if (kvid >= NKV_TILES) return;
    const int it = kvid % NKT, bh = kvid / NKT;
    const int kb = it * KVB;
    const float* kp = kg + (size_t)bh * S_LEN * DH;
    const float* vp = vg + (size_t)bh * S_LEN * DH;
    __bf16* kout = Kb + ((size_t)bh * NKT + it) * TILE_E;
    __bf16* vout = Vb + ((size_t)bh * NKT + it) * TILE_E;

    // K rows permuted+swizzled
    for (int i = tid; i < 512; i += 256) {
      const int rho = i >> 3, gx = i & 7;
      const int e = ((rho & 15) << 2) | (rho >> 4);
      const int key = kb + e;
      const int gsrc = gx ^ (rho & 7);
      float4 a = {0.f, 0.f, 0.f, 0.f}, b = {0.f, 0.f, 0.f, 0.f};
      if (key < S_LEN) {
        a = *(const float4*)(kp + (size_t)key * DH + gsrc * 8);
        b = *(const float4*)(kp + (size_t)key * DH + gsrc * 8 + 4);
      }
      *(bf16x8*)(kout + (size_t)rho * 64 + gx * 8) = cvt_bf16x8(a, b);
    }

    // V transpose through LDS
    float(*vt)[68] = (float(*)[68])smem;
    for (int i = tid; i < 1024; i += 256) {
      const int row = i >> 4, c4 = i & 15;
      const int key = kb + row;
      float4 a = {0.f, 0.f, 0.f, 0.f};
      if (key < S_LEN) a = *(const float4*)(vp + (size_t)key * DH + c4 * 4);
      *(float4*)&vt[row][c4 * 4] = a;
    }
    __syncthreads();
    for (int i = tid; i < 512; i += 256) {
      const int d = i >> 3, gx = i & 7;
      const int kg8 = (gx ^ (d & 7)) * 8;
      bf16x8 o;
#pragma unroll
      for (int j = 0; j < 8; ++j) o[j] = (__bf16)vt[kg8 + j][d];
      *(bf16x8*)(vout + (size_t)d * 64 + gx * 8) = o;
    }
  }
}

// ---------------- flash attention v4x2: v4 body + XCD map + setprio ---------
#define TILE_STEP(ITC, MASKED) do {                                           \
    const int buf_ = (ITC) & 1;                                               \
    const int kk_ = (ITC) * KVB + 4 * m;                                      \
    bf16x4 bias4_[4];                                                         \
    _Pragma("unroll")                                                         \
    for (int r = 0; r < 4; ++r) {                                             \
      bf16x4 z_; z_[0] = (__bf16)0.f; z_[1] = (__bf16)0.f;                    \
      z_[2] = (__bf16)0.f; z_[3] = (__bf16)0.f;                               \
      bias4_[r] = (!(MASKED) || kk_ < S_LEN)                                  \
                      ? *(const bf16x4*)(brow[r] + kk_) : z_;                 \
    }                                                                         \
    __builtin_amdgcn_s_barrier();                                             \
    {                                                                         \
      const int nit_ = ((ITC) + 1 < NKT) ? (ITC) + 1 : 0;                     \
      const __bf16* gk_ = KbT + (size_t)nit_ * TILE_E + wave * 1024 + lo16;   \
      const __bf16* gv_ = VbT + (size_t)nit_ * TILE_E + wave * 1024 + lo16;   \
      __bf16* lk_ = &Kt[buf_ ^ 1][0][0] + wave * 1024;                        \
      __bf16* lv_ = &Vt[buf_ ^ 1][0][0] + wave * 1024;                        \
      GLD16(gk_, lk_); GLD16(gk_ + 512, lk_ + 512);                           \
      GLD16(gv_, lv_); GLD16(gv_ + 512, lv_ + 512);                           \
    }                                                                         \
    asm volatile("s_waitcnt vmcnt(8)" ::: "memory");                          \
    __builtin_amdgcn_s_barrier();                                             \
    __builtin_amdgcn_sched_barrier(0x7); /* ALU may cross; memory may not */  \
    f32x4 sc_[4];                                                             \
    __builtin_amdgcn_s_setprio(1);                                            \
    _Pragma("unroll")                                                         \
    for (int c = 0; c < 4; ++c) {                                             \
      f32x4 a_;                                                               \
      _Pragma("unroll")                                                       \
      for (int r = 0; r < 4; ++r) a_[r] = (float)bias4_[r][c];                \
      _Pragma("unroll")                                                       \
      for (int dc = 0; dc < 2; ++dc) {                                        \
        bf16x8 kf_ = *(bf16x8*)&Kt[buf_][c * 16 + m][(dc * 32 + g * 8) ^ sw_m]; \
        a_ = mfma16(qf[dc], kf_, a_);                                         \
      }                                                                       \
      sc_[c] = a_;                                                            \
    }                                                                         \
    __builtin_amdgcn_s_setprio(0);                                            \
    _Pragma("unroll")                                                         \
    for (int r = 0; r < 4; ++r) {                                             \
      float p0_ = exp2_fast(sc_[0][r]);                                       \
      float p1_ = exp2_fast(sc_[1][r]);                                       \
      float p2_ = exp2_fast(sc_[2][r]);                                       \
      float p3_ = exp2_fast(sc_[3][r]);                                       \
      if (MASKED) {                                                           \
        const float kvf_ = (kk_ < S_LEN) ? 1.f : 0.f;                         \
        lsum[r] += kvf_ * ((p0_ + p1_) + (p2_ + p3_));                        \
      } else {                                                                \
        lsum[r] += (p0_ + p1_) + (p2_ + p3_);                                 \
      }                                                                       \
      bf16x4 pb_;                                                             \
      pb_[0] = (__bf16)p0_; pb_[1] = (__bf16)p1_;                             \
      pb_[2] = (__bf16)p2_; pb_[3] = (__bf16)p3_;                             \
      const int row_ = g * 4 + r;                                             \
      *(bf16x4*)&Pl[wave][row_][(4 * m) ^ ((row_ & 7) << 3)] = pb_;           \
    }                                                                         \
    __builtin_amdgcn_s_setprio(1);                                            \
    _Pragma("unroll")                                                         \
    for (int kc = 0; kc < 2; ++kc) {                                          \
      bf16x8 pf_ = *(bf16x8*)&Pl[wave][m][(kc * 32 + g * 8) ^ sw_m];          \
      _Pragma("unroll")                                                       \
      for (int t = 0; t < 4; ++t) {                                           \
        bf16x8 vf_ = *(bf16x8*)&Vt[buf_][t * 16 + m][(kc * 32 + g * 8) ^ sw_m]; \
        acc_o[t] = mfma16(pf_, vf_, acc_o[t]);                                \
      }                                                                       \
    }                                                                         \
    __builtin_amdgcn_s_setprio(0);                                            \
  } while (0)

__global__ __launch_bounds__(256, 4) void flex_attn_v4x(
    const float* __restrict__ qg, const __bf16* __restrict__ Kb,
    const __bf16* __restrict__ Vb, const __bf16* __restrict__ biasG,
    float* __restrict__ out) {
  // XCD-aware map: linear id = h + 16*y -> id%8 = h%8, so each XCD
  // serves 2 heads and their bias planes stay L2-resident.
  const int h = blockIdx.x;
  const int y = blockIdx.y;
  const int qt = y % NQT;
  const int b = y / NQT;
  const int bh = b * NHEAD + h;
  const int tid = threadIdx.x;
  const int wave = tid >> 6, lane = tid & 63;
  const int g = lane >> 4, m = lane & 15;

  __shared__ __align__(16) __bf16 Kt[2][KVB][64];   // 16 KB
  __shared__ __align__(16) __bf16 Vt[2][DH][64];    // 16 KB
  __shared__ __align__(16) __bf16 Pl[4][16][64];    // 8 KB

  const __bf16* KbT = Kb + (size_t)bh * NKT * TILE_E;
  const __bf16* VbT = Vb + (size_t)bh * NKT * TILE_E;
  const __bf16* bp = biasG + (size_t)h * SPLANE;
  const float* qp = qg + (size_t)bh * S_LEN * DH;

  // Q fragments, pre-scaled by Dh^-0.5 * log2(e)
  const int qrow = qt * 64 + wave * 16 + m;
  const float qs = 0.125f * LOG2E;
  bf16x8 qf[2];
#pragma unroll
  for (int dc = 0; dc < 2; ++dc) {
    float4 a = {0.f, 0.f, 0.f, 0.f}, bb = {0.f, 0.f, 0.f, 0.f};
    if (qrow < S_LEN) {
      a = *(const float4*)(qp + (size_t)qrow * DH + dc * 32 + g * 8);
      bb = *(const float4*)(qp + (size_t)qrow * DH + dc * 32 + g * 8 + 4);
    }
    a.x *= qs; a.y *= qs; a.z *= qs; a.w *= qs;
    bb.x *= qs; bb.y *= qs; bb.z *= qs; bb.w *= qs;
    qf[dc] = cvt_bf16x8(a, bb);
  }

  const int qb4 = qt * 64 + wave * 16 + g * 4;
  const __bf16* brow[4];
#pragma unroll
  for (int r = 0; r < 4; ++r) {
    int qq = qb4 + r; if (qq > S_LEN - 1) qq = S_LEN - 1;
    brow[r] = bp + (size_t)qq * SPITCH;
  }

  f32x4 acc_o[4];
#pragma unroll
  for (int t = 0; t < 4; ++t) acc_o[t] = (f32x4){0.f, 0.f, 0.f, 0.f};
  float lsum[4] = {0.f, 0.f, 0.f, 0.f};

  const int sw_m = (m & 7) << 3;
  const int lo16 = lane * 8;

  // prologue: stage tile 0 into buf 0
  {
    const __bf16* gk = KbT + wave * 1024 + lo16;
    const __bf16* gv = VbT + wave * 1024 + lo16;
    __bf16* lk = &Kt[0][0][0] + wave * 1024;
    __bf16* lv = &Vt[0][0][0] + wave * 1024;
    GLD16(gk, lk); GLD16(gk + 512, lk + 512);
    GLD16(gv, lv); GLD16(gv + 512, lv + 512);
  }

#pragma unroll 2
  for (int it = 0; it < 16; ++it) {
    TILE_STEP(it, false);
  }
  TILE_STEP(16, true);

  // epilogue: reduce lsum across the 16 m-lanes, write O
#pragma unroll
  for (int r = 0; r < 4; ++r) {
    float s = lsum[r];
    s += __shfl_xor(s, 1);
    s += __shfl_xor(s, 2);
    s += __shfl_xor(s, 4);
    s += __shfl_xor(s, 8);
    const int qq = qb4 + r;
    if (qq >= S_LEN) continue;
    const float inv = 1.f / s;
    float* op = out + (((size_t)bh) * S_LEN + qq) * DH;
#pragma unroll
    for (int t = 0; t < 4; ++t) op[t * 16 + m] = acc_o[t][r] * inv;
  }
}

// ================= fallback (ws too small for packed KV) =====================
__global__ __launch_bounds__(256) void bias_expand2(const int* __restrict__ idx,
                                                    const float* __restrict__ bt,
                                                    const int* __restrict__ Rp,
                                                    __bf16* __restrict__ bias) {
  const int qrow = blockIdx.x;
  const int R = Rp[0];
  const bool qok = (qrow >= R);
  const int tid = threadIdx.x;
  __shared__ __align__(16) __bf16 strip[NHEAD][264];
  for (int k0 = 0; k0 < 1024; k0 += 256) {
    const int k = k0 + tid;
    const int l = idx[(size_t)qrow * S_LEN + k];
    const bool on = qok && (k >= R);
    const float4* btv = (const float4*)bt + (size_t)l * 4;
    float va[16];
    *(float4*)&va[0] = btv[0];
    *(float4*)&va[4] = btv[1];
    *(float4*)&va[8] = btv[2];
    *(float4*)&va[12] = btv[3];
#pragma unroll
    for (int h = 0; h < NHEAD; ++h)
      strip[h][tid] = on ? (__bf16)(va[h] * LOG2E) : (__bf16)0.f;
    __syncthreads();
    {
      const int h = tid >> 4, kg2 = tid & 15;
      bf16x8 w0 = *(bf16x8*)&strip[h][kg2 * 16];
      bf16x8 w1 = *(bf16x8*)&strip[h][kg2 * 16 + 8];
      __bf16* dst = bias + (size_t)h * S_LEN * S_LEN + (size_t)qrow * S_LEN + k0 + kg2 * 16;
      *(bf16x8*)dst = w0;
      *(bf16x8*)(dst + 8) = w1;
    }
    __syncthreads();
  }
  if (tid < 64) {
    const int kt = tid & 3, h = tid >> 2;
    const int k = 1024 + kt;
    const int l = idx[(size_t)qrow * S_LEN + k];
    const bool on = qok && (k >= R);
    const float v = bt[(size_t)l * NHEAD + h];
    bias[(size_t)h * S_LEN * S_LEN + (size_t)qrow * S_LEN + k] =
        on ? (__bf16)(v * LOG2E) : (__bf16)0.f;
  }
}

__global__ __launch_bounds__(256, 4) void flex_attn_fast(
    const float* __restrict__ qg, const float* __restrict__ kg,
    const float* __restrict__ vg, const __bf16* __restrict__ biasG,
    float* __restrict__ out) {
  const int b = blockIdx.z, h = blockIdx.y, qt = blockIdx.x;
  const int tid = threadIdx.x;
  const int wave = tid >> 6, lane = tid & 63;
  const int g = lane >> 4, m = lane & 15;

  __shared__ __align__(16) __bf16 Kt[KVB][72];
  __shared__ __align__(16) __bf16 Vt[DH][72];
  __shared__ __align__(16) __bf16 Pl[4][16][72];

  const size_t base = ((size_t)(b * NHEAD + h)) * S_LEN * DH;
  const float* qp = qg + base;
  const float* kp = kg + base;
  const float* vp = vg + base;
  const __bf16* bp = biasG + (size_t)h * S_LEN * S_LEN;

  const int qrow = qt * 64 + wave * 16 + m;
  const float qs = 0.125f * LOG2E;
  bf16x8 qf[2];
#pragma unroll
  for (int dc = 0; dc < 2; ++dc) {
    float4 a = {0.f, 0.f, 0.f, 0.f}, bb = {0.f, 0.f, 0.f, 0.f};
    if (qrow < S_LEN) {
      a = *(const float4*)(qp + (size_t)qrow * DH + dc * 32 + g * 8);
      bb = *(const float4*)(qp + (size_t)qrow * DH + dc * 32 + g * 8 + 4);
    }
    a.x *= qs; a.y *= qs; a.z *= qs; a.w *= qs;
    bb.x *= qs; bb.y *= qs; bb.z *= qs; bb.w *= qs;
    qf[dc] = cvt_bf16x8(a, bb);
  }

  f32x4 acc_o[4];
#pragma unroll
  for (int t = 0; t < 4; ++t) acc_o[t] = (f32x4){0.f, 0.f, 0.f, 0.f};
  float mrow[4], lrow[4];
#pragma unroll
  for (int r = 0; r < 4; ++r) { mrow[r] = -1e30f; lrow[r] = 0.f; }

  const int qb4 = qt * 64 + wave * 16 + g * 4;
  const int eK = wave * 16 + (lane >> 2);
  const int rowK = ((eK & 3) << 4) | (eK >> 2);
  const int colK = (lane & 3) * 16;

  for (int it = 0; it < NKT; ++it) {
    const int kb = it * KVB;
    __syncthreads();
    {
      const int krow = kb + eK;
      float4 a0 = {0,0,0,0}, a1 = {0,0,0,0}, a2 = {0,0,0,0}, a3 = {0,0,0,0};
      if (krow < S_LEN) {
        const float* src = kp + (size_t)krow * DH + colK;
        a0 = *(const float4*)(src);
        a1 = *(const float4*)(src + 4);
        a2 = *(const float4*)(src + 8);
        a3 = *(const float4*)(src + 12);
      }
      *(bf16x8*)&Kt[rowK][colK] = cvt_bf16x8(a0, a1);
      *(bf16x8*)&Kt[rowK][colK + 8] = cvt_bf16x8(a2, a3);
    }
    {
      bf16x8 p0, p1;
#pragma unroll
      for (int t = 0; t < 8; ++t) {
        const int kr = kb + wave * 16 + t;
        p0[t] = (kr < S_LEN) ? (__bf16)vp[(size_t)kr * DH + lane] : (__bf16)0.f;
      }
#pragma unroll
      for (int t = 0; t < 8; ++t) {
        const int kr = kb + wave * 16 + 8 + t;
        p1[t] = (kr < S_LEN) ? (__bf16)vp[(size_t)kr * DH + lane] : (__bf16)0.f;
      }
      *(bf16x8*)&Vt[lane][wave * 16] = p0;
      *(bf16x8*)&Vt[lane][wave * 16 + 8] = p1;
    }

    const int kk = kb + 4 * m;
    const bool kvalid = (kk < S_LEN);
    bf16x4 bias4[4];
#pragma unroll
    for (int r = 0; r < 4; ++r) {
      const int qq = (qb4 + r < S_LEN) ? qb4 + r : S_LEN - 1;
      bf16x4 z; z[0] = (__bf16)0.f; z[1] = (__bf16)0.f; z[2] = (__bf16)0.f; z[3] = (__bf16)0.f;
      bias4[r] = kvalid ? *(const bf16x4*)(bp + (size_t)qq * S_LEN + kk) : z;
    }

    __syncthreads();

    f32x4 sc[4];
#pragma unroll
    for (int c = 0; c < 4; ++c) {
      f32x4 a = (f32x4){0.f, 0.f, 0.f, 0.f};
#pragma unroll
      for (int dc = 0; dc < 2; ++dc) {
        bf16x8 kf = *(bf16x8*)&Kt[c * 16 + m][dc * 32 + g * 8];
        a = mfma16(qf[dc], kf, a);
      }
      sc[c] = a;
    }

#pragma unroll
    for (int r = 0; r < 4; ++r) {
      float s[4];
#pragma unroll
      for (int c = 0; c < 4; ++c)
        s[c] = kvalid ? sc[c][r] + (float)bias4[r][c] : -1e30f;
      float mx = fmaxf(fmaxf(s[0], s[1]), fmaxf(s[2], s[3]));
      mx = fmaxf(mx, __shfl_xor(mx, 1));
      mx = fmaxf(mx, __shfl_xor(mx, 2));
      mx = fmaxf(mx, __shfl_xor(mx, 4));
      mx = fmaxf(mx, __shfl_xor(mx, 8));
      const float mnew = fmaxf(mrow[r], mx);
      const float alpha = exp2_fast(mrow[r] - mnew);
      float p0 = exp2_fast(s[0] - mnew), p1 = exp2_fast(s[1] - mnew);
      float p2 = exp2_fast(s[2] - mnew), p3 = exp2_fast(s[3] - mnew);
      float sum = (p0 + p1) + (p2 + p3);
      sum += __shfl_xor(sum, 1);
      sum += __shfl_xor(sum, 2);
      sum += __shfl_xor(sum, 4);
      sum += __shfl_xor(sum, 8);
      lrow[r] = lrow[r] * alpha + sum;
      mrow[r] = mnew;
      bf16x4 pb;
      pb[0] = (__bf16)p0; pb[1] = (__bf16)p1; pb[2] = (__bf16)p2; pb[3] = (__bf16)p3;
      *(bf16x4*)&Pl[wave][g * 4 + r][4 * m] = pb;
#pragma unroll
      for (int t = 0; t < 4; ++t) acc_o[t][r] *= alpha;
    }

#pragma unroll
    for (int kc = 0; kc < 2; ++kc) {
      bf16x8 pf = *(bf16x8*)&Pl[wave][m][kc * 32 + g * 8];
#pragma unroll
      for (int t = 0; t < 4; ++t) {
        bf16x8 vf = *(bf16x8*)&Vt[t * 16 + m][kc * 32 + g * 8];
        acc_o[t] = mfma16(pf, vf, acc_o[t]);
      }
    }
  }

#pragma unroll
  for (int r = 0; r < 4; ++r) {
    const int qq = qb4 + r;
    if (qq >= S_LEN) continue;
    const float inv = 1.f / lrow[r];
    float* op = out + (((size_t)(b * NHEAD + h)) * S_LEN + qq) * DH;
#pragma unroll
    for (int t = 0; t < 4; ++t) op[t * 16 + m] = acc_o[t][r] * inv;
  }
}

extern "C" void kernel_launch(void* const* d_in, const int* in_sizes, int n_in,
                              void* d_out, int out_size, void* d_ws, size_t ws_size,
                              hipStream_t stream) {
  const float* q = (const float*)d_in[0];
  const float* k = (const float*)d_in[1];
  const float* v = (const float*)d_in[2];
  const float* rel = (const float*)d_in[3];
  const float* W1 = (const float*)d_in[4];
  const float* b1 = (const float*)d_in[5];
  const float* W2 = (const float*)d_in[6];
  const int* idx = (const int*)d_in[7];
  const int* Rp = (const int*)d_in[8];
  float* out = (float*)d_out;

  const size_t bt_bytes = 1u << 18;                                   // 256 KB slot (f32)
  const size_t bt16_bytes = 1u << 17;                                 // 128 KB slot (bf16)
  const size_t bias_bytes = (size_t)NHEAD * SPLANE * 2;               // 34.2 MB (padded)
  const size_t kv_bytes = (size_t)NBATCH * NHEAD * NKT * TILE_E * 2;  // 17.8 MB each

  float* bt = (float*)d_ws;
  __bf16* bt16 = (__bf16*)((char*)d_ws + bt_bytes);
  __bf16* bias = (__bf16*)((char*)d_ws + bt_bytes + bt16_bytes);
  __bf16* Kb = (__bf16*)((char*)d_ws + bt_bytes + bt16_bytes + bias_bytes);
  __bf16* Vb = (__bf16*)((char*)d_ws + bt_bytes + bt16_bytes + bias_bytes + kv_bytes);

  if (ws_size >= bt_bytes + bt16_bytes + bias_bytes + 2 * kv_bytes) {
    cpb_table_lh<<<dim3((L2N + 255) / 256), dim3(256), 0, stream>>>(rel, W1, b1, W2, bt, bt16);
    prep_fused3<<<dim3(4232), dim3(256), 0, stream>>>(idx, bt16, Rp, k, v, bias, Kb, Vb);
    flex_attn_v4x<<<dim3(NHEAD, NQT * NBATCH, 1), dim3(256), 0, stream>>>(q, Kb, Vb, bias, out);
  } else {
    // fallback: f32 bt + unpacked KV (kernels proven in round 2/5)
    __bf16* bias_f = (__bf16*)((char*)d_ws + bt_bytes + bt16_bytes);
    cpb_table_lh<<<dim3((L2N + 255) / 256), dim3(256), 0, stream>>>(rel, W1, b1, W2, bt, bt16);
    bias_expand2<<<dim3(S_LEN), dim3(256), 0, stream>>>(idx, bt, Rp, bias_f);
    flex_attn_fast<<<dim3(NQT, NHEAD, NBATCH), dim3(256), 0, stream>>>(q, k, v, bias_f, out);
  }
}